// Round 20
// baseline (1677.843 us; speedup 1.0000x reference)
//
#include <hip/hip_runtime.h>
#include <hip/hip_bf16.h>
#include <hip/hip_cooperative_groups.h>
#include <cstdint>
#include <cstddef>

namespace cg = cooperative_groups;

// ---------------------------------------------------------------------------
// E3nnMLPNorm: only the l=1 (d=3) irrep path is nonzero.
// R20: COOPERATIVE MEGA-KERNEL. R17's gemm (K-split x2 direct-to-register,
// ~28us = ~80% of per-XCD L2 BW) is kept verbatim; the 5-layer loop
// [gemm -> act] plus the final dot run inside ONE cooperative launch with
// grid.sync() between phases - eliminating ~20 dispatch boundaries and the
// non-gemm launch overhead (measured 55us of non-gemm time at R17).
// Fallback to the R17 dispatch sequence if cooperative launch fails.
// ---------------------------------------------------------------------------

typedef short    s16x8 __attribute__((ext_vector_type(8)));
typedef float    f32x4 __attribute__((ext_vector_type(4)));

#define PLANE 1048576   // 1024*1024 elements per plane

__device__ __forceinline__ unsigned short f2bf(float f) {
  unsigned u = __builtin_bit_cast(unsigned, f);
  u += 0x7FFFu + ((u >> 16) & 1u);              // round-to-nearest-even
  return (unsigned short)(u >> 16);
}
__device__ __forceinline__ float bf2f(unsigned short h) {
  return __builtin_bit_cast(float, (unsigned)h << 16);
}

// byte offset of element (row, k) in the K-blocked bf16 operand layout:
// [row>>6][k>>5][(row>>4)&3][(k>>3)&3][row&15][k&7]
__device__ __forceinline__ size_t ablk(int row, int k) {
  return ((size_t)(row >> 6) << 17) + ((size_t)(k >> 5) << 12)
       + ((size_t)((row >> 4) & 3) << 10) + ((size_t)((k >> 3) & 3) << 8)
       + ((size_t)(row & 15) << 4) + ((size_t)(k & 7) << 1);
}

// ---- W[b,0] (f32 [u][v]) -> blocked bf16 hi/lo (row=v, k=u), 1/32 folded ----
__global__ void convert_w(const float* __restrict__ W,
                          unsigned short* __restrict__ Wh,
                          unsigned short* __restrict__ Wl) {
  __shared__ float t[64][65];
  const int u0 = blockIdx.x * 64, v0 = blockIdx.y * 64;
  const float* Wb = W + (size_t)blockIdx.z * 4194304;   // [5][4][1024][1024], irrep 0
  char* Whb = (char*)(Wh + (size_t)blockIdx.z * PLANE);
  char* Wlb = (char*)(Wl + (size_t)blockIdx.z * PLANE);
  const int c = threadIdx.x & 63, r4 = threadIdx.x >> 6;
#pragma unroll
  for (int i = 0; i < 16; ++i) {
    const int r = i * 4 + r4;
    t[r][c] = Wb[(size_t)(u0 + r) * 1024 + v0 + c];
  }
  __syncthreads();
#pragma unroll
  for (int i = 0; i < 16; ++i) {
    const int r = i * 4 + r4;   // local v index
    const float w = t[c][r] * 0.03125f;      // exact pow2 scale
    const unsigned short hi = f2bf(w);
    const size_t off = ablk(v0 + r, u0 + c);
    *(unsigned short*)(Whb + off) = hi;
    *(unsigned short*)(Wlb + off) = f2bf(w - bf2f(hi));
  }
}

// ---- layer0 + fused colsumsq: pre[i][b][v] (linear f32), var[v] += sum f^2 --
__global__ void layer0_fused(const float* __restrict__ x, const float* __restrict__ w1,
                             float* __restrict__ pre, float* __restrict__ var) {
  const int v = blockIdx.x * 256 + threadIdx.x;
  const int b0 = blockIdx.y * 16;
  const float a0 = w1[v], a1 = w1[1024 + v];
  const float inv = 0.70710678118654752f;
  float ssq = 0.f;
#pragma unroll 4
  for (int bb = 0; bb < 16; ++bb) {
    const int b = b0 + bb;
    const float* xb = x + b * 6;                    // x flat [B][2][3]
#pragma unroll
    for (int i = 0; i < 3; ++i) {
      const float f = (xb[i] * a0 + xb[3 + i] * a1) * inv;
      pre[(size_t)i * PLANE + (size_t)b * 1024 + v] = f;
      ssq += f * f;
    }
  }
  atomicAdd(&var[v], ssq);
}

// ---- act math shared by the standalone kernel and the mega phase -----------
__device__ __forceinline__ void act_unit(const float* __restrict__ pre,
                                         const float* __restrict__ var,
                                         const float* __restrict__ bnw,
                                         char* __restrict__ ah, char* __restrict__ al,
                                         int b, int v0) {
  float s[8];
#pragma unroll
  for (int j = 0; j < 8; ++j)
    s[j] = bnw[v0 + j] / sqrtf(var[v0 + j] * (1.0f / 3072.0f) + 1e-5f);
  float f[3][8];
#pragma unroll
  for (int i = 0; i < 3; ++i) {
    const float4 p0 = *(const float4*)&pre[(size_t)i * PLANE + (size_t)b * 1024 + v0];
    const float4 p1 = *(const float4*)&pre[(size_t)i * PLANE + (size_t)b * 1024 + v0 + 4];
    f[i][0] = p0.x * s[0]; f[i][1] = p0.y * s[1]; f[i][2] = p0.z * s[2]; f[i][3] = p0.w * s[3];
    f[i][4] = p1.x * s[4]; f[i][5] = p1.y * s[5]; f[i][6] = p1.z * s[6]; f[i][7] = p1.w * s[7];
  }
#pragma unroll
  for (int j = 0; j < 8; ++j) {
    const float n = sqrtf(f[0][j] * f[0][j] + f[1][j] * f[1][j] + f[2][j] * f[2][j] + 1e-8f);
    const float g = 1.0f / ((1.0f + expf(-n)) * n);   // sigmoid(n)/n
    f[0][j] *= g; f[1][j] *= g; f[2][j] *= g;
  }
#pragma unroll
  for (int i = 0; i < 3; ++i) {
    s16x8 hi, lo;
#pragma unroll
    for (int j = 0; j < 8; ++j) {
      const unsigned short h = f2bf(f[i][j]);
      hi[j] = (short)h;
      lo[j] = (short)f2bf(f[i][j] - bf2f(h));
    }
    const size_t off = ablk(i * 1024 + b, v0);
    *(s16x8*)(ah + off) = hi;
    *(s16x8*)(al + off) = lo;
  }
}

// ---- standalone act (layer 0 + fallback path) -------------------------------
__global__ void act_kernel(const float* __restrict__ pre, const float* __restrict__ var,
                           const float* __restrict__ bnw,
                           char* __restrict__ ah, char* __restrict__ al) {
  const int tid = threadIdx.x;
  const int b  = blockIdx.x * 16 + (tid & 15);
  const int v0 = blockIdx.y * 128 + (tid >> 4) * 8;
  act_unit(pre, var, bnw, ah, al, b, v0);
}

#define LOADF(A_, B_, t_)                                                      \
  {                                                                            \
    const size_t kb_ = (size_t)(t_) << 12;                                     \
    _Pragma("unroll")                                                          \
    for (int m_ = 0; m_ < 4; ++m_) {                                           \
      A_[m_]     = *(const s16x8*)(a_h + kb_ + (m_ << 10));                    \
      A_[4 + m_] = *(const s16x8*)(a_l + kb_ + (m_ << 10));                    \
      B_[m_]     = *(const s16x8*)(b_h + kb_ + (m_ << 10));                    \
      B_[4 + m_] = *(const s16x8*)(b_l + kb_ + (m_ << 10));                    \
    }                                                                          \
  }
#define COMPUTEF(A_, B_)                                                       \
  {                                                                            \
    _Pragma("unroll")                                                          \
    for (int m_ = 0; m_ < 4; ++m_)                                             \
      _Pragma("unroll")                                                        \
      for (int n_ = 0; n_ < 4; ++n_) {                                         \
        acc[m_][n_] = __builtin_amdgcn_mfma_f32_16x16x32_bf16(                 \
            A_[4 + m_], B_[n_], acc[m_][n_], 0, 0, 0);                         \
        acc[m_][n_] = __builtin_amdgcn_mfma_f32_16x16x32_bf16(                 \
            A_[m_], B_[4 + n_], acc[m_][n_], 0, 0, 0);                         \
        acc[m_][n_] = __builtin_amdgcn_mfma_f32_16x16x32_bf16(                 \
            A_[m_], B_[n_], acc[m_][n_], 0, 0, 0);                             \
      }                                                                        \
  }

// ---- R17 gemm phase as a device function (used by mega and fallback) --------
__device__ __forceinline__ void gemm_phase(
    const char* __restrict__ Ah, const char* __restrict__ Al,
    const char* __restrict__ Bh, const char* __restrict__ Bl,
    float* __restrict__ C, float* __restrict__ var, float* red) {
  const int bid = blockIdx.x;
  const int xcd = bid & 7, q = bid >> 3;          // q in 0..95
  const int tm = xcd * 6 + (q % 6);               // 0..47 (XCD M-stripe)
  const int tn = q / 6;                           // 0..15
  const int lane = threadIdx.x & 63;
  const int wave = threadIdx.x >> 6;              // K-half owner: 0 or 1
  const int rsel = lane & 15, kcsel = lane >> 4;

  const size_t la = ((size_t)lane << 4) + ((size_t)wave << 16);
  const char* a_h = Ah + ((size_t)tm << 17) + la;
  const char* a_l = Al + ((size_t)tm << 17) + la;
  const char* b_h = Bh + ((size_t)tn << 17) + la;
  const char* b_l = Bl + ((size_t)tn << 17) + la;

  f32x4 acc[4][4] = {};
  s16x8 A0[8], B0[8], A1[8], B1[8];

  LOADF(A0, B0, 0);
  LOADF(A1, B1, 1);
  for (int t = 0; t < 14; t += 2) {
    COMPUTEF(A0, B0);
    LOADF(A0, B0, t + 2);
    COMPUTEF(A1, B1);
    LOADF(A1, B1, t + 3);
  }
  COMPUTEF(A0, B0);              // step 14
  COMPUTEF(A1, B1);              // step 15

  if (wave == 1) {
#pragma unroll
    for (int m = 0; m < 4; ++m)
#pragma unroll
      for (int n = 0; n < 4; ++n)
#pragma unroll
        for (int j = 0; j < 4; ++j)
          red[(((((m << 2) | n) << 2) | j) << 6) | lane] = acc[m][n][j];
  }
  __syncthreads();
  if (wave == 0) {
    const int r0 = tm * 64 + (kcsel << 2);
    const int c0 = tn * 64 + rsel;
    float csq[4] = {0.f, 0.f, 0.f, 0.f};
#pragma unroll
    for (int m = 0; m < 4; ++m)
#pragma unroll
      for (int n = 0; n < 4; ++n)
#pragma unroll
        for (int j = 0; j < 4; ++j) {
          const float v = acc[m][n][j] + red[(((((m << 2) | n) << 2) | j) << 6) | lane];
          C[(size_t)(r0 + m * 16 + j) * 1024 + c0 + n * 16] = v;
          csq[n] += v * v;
        }
#pragma unroll
    for (int n = 0; n < 4; ++n) {
      csq[n] += __shfl_xor(csq[n], 16);
      csq[n] += __shfl_xor(csq[n], 32);
    }
    if (kcsel == 0) {
#pragma unroll
      for (int n = 0; n < 4; ++n)
        atomicAdd(&var[c0 + n * 16], csq[n]);
    }
  }
  __syncthreads();               // red reusable afterwards
}

// ---- fallback standalone gemm (R17) ----------------------------------------
__global__ __launch_bounds__(128, 2) void gemm_reg(
    const char* __restrict__ Ah, const char* __restrict__ Al,
    const char* __restrict__ Bh, const char* __restrict__ Bl,
    float* __restrict__ C, float* __restrict__ var) {
  __shared__ float red[4096];
  gemm_phase(Ah, Al, Bh, Bl, C, var, red);
}

// ---- final dot as device function ------------------------------------------
__device__ __forceinline__ void final_phase(const char* __restrict__ ah,
                                            const char* __restrict__ al,
                                            const float* __restrict__ wout,
                                            float* __restrict__ out, float* red) {
  const int lane = threadIdx.x & 63, wave = threadIdx.x >> 6;
  for (int b = blockIdx.x; b < 1024; b += 768) {
    float s[3] = {0.f, 0.f, 0.f};
    const int v0 = threadIdx.x * 8;                // 128 thr x 8 = 1024 cols
#pragma unroll
    for (int i = 0; i < 3; ++i) {
      const size_t off = ablk(i * 1024 + b, v0);
      const s16x8 hi = *(const s16x8*)(ah + off);
      const s16x8 lo = *(const s16x8*)(al + off);
#pragma unroll
      for (int j = 0; j < 8; ++j)
        s[i] += (bf2f((unsigned short)hi[j]) + bf2f((unsigned short)lo[j])) * wout[v0 + j];
    }
#pragma unroll
    for (int i = 0; i < 3; ++i)
      for (int o = 32; o >= 1; o >>= 1) s[i] += __shfl_down(s[i], o);
    if (lane == 0) {
#pragma unroll
      for (int i = 0; i < 3; ++i) red[wave * 4 + i] = s[i];
    }
    __syncthreads();
    if (threadIdx.x < 3)
      out[b * 3 + threadIdx.x] = (red[threadIdx.x] + red[4 + threadIdx.x]) * 0.03125f;
    __syncthreads();
  }
}

__global__ void final_kernel(const char* __restrict__ ah, const char* __restrict__ al,
                             const float* __restrict__ wout, float* __restrict__ out) {
  __shared__ float red[8];
  final_phase(ah, al, wout, out, red);
}

// ---- the cooperative mega-kernel: 5 x [gemm -> sync -> act -> sync] + final -
__global__ __launch_bounds__(128, 2) void mega(
    char* __restrict__ ah, char* __restrict__ al,
    const char* __restrict__ wh, const char* __restrict__ wl,
    float* __restrict__ pre, float* __restrict__ var,
    const float* __restrict__ bnw, const float* __restrict__ wout,
    float* __restrict__ out) {
  cg::grid_group grid = cg::this_grid();
  __shared__ float red[4096];

  for (int L = 0; L < 5; ++L) {
    gemm_phase(ah, al,
               wh + ((size_t)L << 21), wl + ((size_t)L << 21),
               pre, var + ((size_t)(L + 1) << 10), red);
    __threadfence();
    grid.sync();
    // act phase: 131072 (b, v0/8) units over 98304 threads
    const float* varL = var + ((size_t)(L + 1) << 10);
    const float* bnwL = bnw + (size_t)(L + 1) * 4096;
    for (int u = blockIdx.x * 128 + threadIdx.x; u < 131072; u += 98304)
      act_unit(pre, varL, bnwL, ah, al, u >> 7, (u & 127) << 3);
    __threadfence();
    grid.sync();
  }
  final_phase(ah, al, wout, out, red);
}

extern "C" void kernel_launch(void* const* d_in, const int* in_sizes, int n_in,
                              void* d_out, int out_size, void* d_ws, size_t ws_size,
                              hipStream_t stream) {
  const float* x    = (const float*)d_in[0];
  const float* w1   = (const float*)d_in[1];
  const float* W    = (const float*)d_in[2];
  const float* bnw  = (const float*)d_in[3];
  const float* wout = (const float*)d_in[4];
  float* out = (float*)d_out;

  char* ws = (char*)d_ws;
  float*          var = (float*)ws;                         // 6*1024 f32 (32 KB resv)
  float*          pre = (float*)(ws + 32768);               // C buffer, 12 MB
  char*           ah  = ws + 12615680;                      // blocked bf16 (6 MB)
  char*           al  = ws + 18907136;                      // blocked bf16 (6 MB)
  unsigned short* wh  = (unsigned short*)(ws + 25198592);   // blocked bf16 (10 MB)
  unsigned short* wl  = (unsigned short*)(ws + 35684352);   // blocked bf16 (10 MB)

  hipMemsetAsync(var, 0, 6 * 1024 * sizeof(float), stream);
  convert_w<<<dim3(16, 16, 5), 256, 0, stream>>>(W, wh, wl);
  layer0_fused<<<dim3(4, 64), 256, 0, stream>>>(x, w1, pre, var);
  act_kernel<<<dim3(64, 8), 256, 0, stream>>>(pre, var, bnw, ah, al);

  char* whc = (char*)wh;
  char* wlc = (char*)wl;
  void* args[] = {&ah, &al, &whc, &wlc, &pre, &var,
                  (void*)&bnw, (void*)&wout, &out};
  hipError_t e = hipLaunchCooperativeKernel((const void*)mega, dim3(768), dim3(128),
                                            args, 0, stream);
  if (e != hipSuccess) {
    // fallback: R17 dispatch sequence
    for (int b = 0; b < 5; ++b) {
      gemm_reg<<<768, 128, 0, stream>>>(
          ah, al, whc + ((size_t)b << 21), wlc + ((size_t)b << 21),
          pre, var + (b + 1) * 1024);
      act_kernel<<<dim3(64, 8), 256, 0, stream>>>(pre, var + (b + 1) * 1024,
                                                  bnw + (size_t)(b + 1) * 4096, ah, al);
    }
    final_kernel<<<1024, 256, 0, stream>>>(ah, al, wout, out);
  }
}

// Round 21
// 194.615 us; speedup vs baseline: 8.6213x; 8.6213x over previous
//
#include <hip/hip_runtime.h>
#include <hip/hip_bf16.h>
#include <cstdint>
#include <cstddef>

// ---------------------------------------------------------------------------
// E3nnMLPNorm: only the l=1 (d=3) irrep path is nonzero.
// layer0(+colsumsq) -> [gemm(+colsumsq) -> bn+gate] x5 -> final dot
// Precision: bf16 hi+lo pairs, 3 bf16 MFMA per fragment into f32 acc.
// R21 = R17 verbatim (measured best, 195.3 us). R20's cooperative fusion
// regressed 8x: cross-XCD L2 non-coherence forces grid.sync phases to
// round-trip activations through HBM (FETCH 23->363 MB, MfmaUtil 2.3%).
// R17's gemm: K-split x2 direct-to-register, K-blocked operands (1KB
// contiguous wave loads), XCD M-stripe, 1536 waves = 1.5/SIMD.
// ---------------------------------------------------------------------------

typedef short    s16x8 __attribute__((ext_vector_type(8)));
typedef float    f32x4 __attribute__((ext_vector_type(4)));

#define PLANE 1048576   // 1024*1024 elements per plane

__device__ __forceinline__ unsigned short f2bf(float f) {
  unsigned u = __builtin_bit_cast(unsigned, f);
  u += 0x7FFFu + ((u >> 16) & 1u);              // round-to-nearest-even
  return (unsigned short)(u >> 16);
}
__device__ __forceinline__ float bf2f(unsigned short h) {
  return __builtin_bit_cast(float, (unsigned)h << 16);
}

// byte offset of element (row, k) in the K-blocked bf16 operand layout:
// [row>>6][k>>5][(row>>4)&3][(k>>3)&3][row&15][k&7]
__device__ __forceinline__ size_t ablk(int row, int k) {
  return ((size_t)(row >> 6) << 17) + ((size_t)(k >> 5) << 12)
       + ((size_t)((row >> 4) & 3) << 10) + ((size_t)((k >> 3) & 3) << 8)
       + ((size_t)(row & 15) << 4) + ((size_t)(k & 7) << 1);
}

// ---- W[b,0] (f32 [u][v]) -> blocked bf16 hi/lo (row=v, k=u), 1/32 folded ----
__global__ void convert_w(const float* __restrict__ W,
                          unsigned short* __restrict__ Wh,
                          unsigned short* __restrict__ Wl) {
  __shared__ float t[64][65];
  const int u0 = blockIdx.x * 64, v0 = blockIdx.y * 64;
  const float* Wb = W + (size_t)blockIdx.z * 4194304;   // [5][4][1024][1024], irrep 0
  char* Whb = (char*)(Wh + (size_t)blockIdx.z * PLANE);
  char* Wlb = (char*)(Wl + (size_t)blockIdx.z * PLANE);
  const int c = threadIdx.x & 63, r4 = threadIdx.x >> 6;
#pragma unroll
  for (int i = 0; i < 16; ++i) {
    const int r = i * 4 + r4;
    t[r][c] = Wb[(size_t)(u0 + r) * 1024 + v0 + c];
  }
  __syncthreads();
#pragma unroll
  for (int i = 0; i < 16; ++i) {
    const int r = i * 4 + r4;   // local v index
    const float w = t[c][r] * 0.03125f;      // exact pow2 scale
    const unsigned short hi = f2bf(w);
    const size_t off = ablk(v0 + r, u0 + c);
    *(unsigned short*)(Whb + off) = hi;
    *(unsigned short*)(Wlb + off) = f2bf(w - bf2f(hi));
  }
}

// ---- layer0 + fused colsumsq: pre[i][b][v] (linear f32), var[v] += sum f^2 --
__global__ void layer0_fused(const float* __restrict__ x, const float* __restrict__ w1,
                             float* __restrict__ pre, float* __restrict__ var) {
  const int v = blockIdx.x * 256 + threadIdx.x;
  const int b0 = blockIdx.y * 16;
  const float a0 = w1[v], a1 = w1[1024 + v];
  const float inv = 0.70710678118654752f;
  float ssq = 0.f;
#pragma unroll 4
  for (int bb = 0; bb < 16; ++bb) {
    const int b = b0 + bb;
    const float* xb = x + b * 6;                    // x flat [B][2][3]
#pragma unroll
    for (int i = 0; i < 3; ++i) {
      const float f = (xb[i] * a0 + xb[3 + i] * a1) * inv;
      pre[(size_t)i * PLANE + (size_t)b * 1024 + v] = f;
      ssq += f * f;
    }
  }
  atomicAdd(&var[v], ssq);
}

// ---- batchnorm + norm-gated sigmoid: pre (linear f32) -> blocked bf16 hi/lo -
// block: 16 b x 128 v; thread: b = 16bx + (tid&15), v0 = 128by + (tid>>4)*8.
__global__ void act_kernel(const float* __restrict__ pre, const float* __restrict__ var,
                           const float* __restrict__ bnw,
                           char* __restrict__ ah, char* __restrict__ al) {
  const int tid = threadIdx.x;
  const int b  = blockIdx.x * 16 + (tid & 15);
  const int v0 = blockIdx.y * 128 + (tid >> 4) * 8;
  float s[8];
#pragma unroll
  for (int j = 0; j < 8; ++j)
    s[j] = bnw[v0 + j] / sqrtf(var[v0 + j] * (1.0f / 3072.0f) + 1e-5f);
  float f[3][8];
#pragma unroll
  for (int i = 0; i < 3; ++i) {
    const float4 p0 = *(const float4*)&pre[(size_t)i * PLANE + (size_t)b * 1024 + v0];
    const float4 p1 = *(const float4*)&pre[(size_t)i * PLANE + (size_t)b * 1024 + v0 + 4];
    f[i][0] = p0.x * s[0]; f[i][1] = p0.y * s[1]; f[i][2] = p0.z * s[2]; f[i][3] = p0.w * s[3];
    f[i][4] = p1.x * s[4]; f[i][5] = p1.y * s[5]; f[i][6] = p1.z * s[6]; f[i][7] = p1.w * s[7];
  }
#pragma unroll
  for (int j = 0; j < 8; ++j) {
    const float n = sqrtf(f[0][j] * f[0][j] + f[1][j] * f[1][j] + f[2][j] * f[2][j] + 1e-8f);
    const float g = 1.0f / ((1.0f + expf(-n)) * n);   // sigmoid(n)/n
    f[0][j] *= g; f[1][j] *= g; f[2][j] *= g;
  }
#pragma unroll
  for (int i = 0; i < 3; ++i) {
    s16x8 hi, lo;
#pragma unroll
    for (int j = 0; j < 8; ++j) {
      const unsigned short h = f2bf(f[i][j]);
      hi[j] = (short)h;
      lo[j] = (short)f2bf(f[i][j] - bf2f(h));
    }
    const size_t off = ablk(i * 1024 + b, v0);
    *(s16x8*)(ah + off) = hi;
    *(s16x8*)(al + off) = lo;
  }
}

// ---- K-split x2 direct-to-register bf16-pair MFMA GEMM + fused colsumsq -----
// 2 waves per block; wave k owns K in [512k, 512k+512) of the block's 64x64
// tile (4x4 frags). Fragments loaded global->VGPR. LDS only for the final
// cross-wave accumulator handoff (16 KB).
#define LOADF(A_, B_, t_)                                                      \
  {                                                                            \
    const size_t kb_ = (size_t)(t_) << 12;                                     \
    _Pragma("unroll")                                                          \
    for (int m_ = 0; m_ < 4; ++m_) {                                           \
      A_[m_]     = *(const s16x8*)(a_h + kb_ + (m_ << 10));                    \
      A_[4 + m_] = *(const s16x8*)(a_l + kb_ + (m_ << 10));                    \
      B_[m_]     = *(const s16x8*)(b_h + kb_ + (m_ << 10));                    \
      B_[4 + m_] = *(const s16x8*)(b_l + kb_ + (m_ << 10));                    \
    }                                                                          \
  }
#define COMPUTEF(A_, B_)                                                       \
  {                                                                            \
    _Pragma("unroll")                                                          \
    for (int m_ = 0; m_ < 4; ++m_)                                             \
      _Pragma("unroll")                                                        \
      for (int n_ = 0; n_ < 4; ++n_) {                                         \
        acc[m_][n_] = __builtin_amdgcn_mfma_f32_16x16x32_bf16(                 \
            A_[4 + m_], B_[n_], acc[m_][n_], 0, 0, 0);                         \
        acc[m_][n_] = __builtin_amdgcn_mfma_f32_16x16x32_bf16(                 \
            A_[m_], B_[4 + n_], acc[m_][n_], 0, 0, 0);                         \
        acc[m_][n_] = __builtin_amdgcn_mfma_f32_16x16x32_bf16(                 \
            A_[m_], B_[n_], acc[m_][n_], 0, 0, 0);                             \
      }                                                                        \
  }

__global__ __launch_bounds__(128, 2) void gemm_reg(
    const char* __restrict__ Ah, const char* __restrict__ Al,
    const char* __restrict__ Bh, const char* __restrict__ Bl,
    float* __restrict__ C, float* __restrict__ var) {
  __shared__ float red[4096];                     // 16 KB cross-wave handoff
  const int bid = blockIdx.x;
  const int xcd = bid & 7, q = bid >> 3;          // q in 0..95
  const int tm = xcd * 6 + (q % 6);               // 0..47 (XCD M-stripe)
  const int tn = q / 6;                           // 0..15
  const int lane = threadIdx.x & 63;
  const int wave = threadIdx.x >> 6;              // K-half owner: 0 or 1
  const int rsel = lane & 15, kcsel = lane >> 4;

  // fragment base pointers: + wave's K-half (16 K-steps x 4KB = 64KB = <<16)
  const size_t la = ((size_t)lane << 4) + ((size_t)wave << 16);
  const char* a_h = Ah + ((size_t)tm << 17) + la;
  const char* a_l = Al + ((size_t)tm << 17) + la;
  const char* b_h = Bh + ((size_t)tn << 17) + la;
  const char* b_l = Bl + ((size_t)tn << 17) + la;

  f32x4 acc[4][4] = {};
  s16x8 A0[8], B0[8], A1[8], B1[8];

  LOADF(A0, B0, 0);
  LOADF(A1, B1, 1);
  for (int t = 0; t < 14; t += 2) {
    COMPUTEF(A0, B0);            // step t
    LOADF(A0, B0, t + 2);
    COMPUTEF(A1, B1);            // step t+1
    LOADF(A1, B1, t + 3);        // last iter loads step 15
  }
  COMPUTEF(A0, B0);              // step 14
  COMPUTEF(A1, B1);              // step 15

  // cross-wave combine: wave1 -> LDS -> wave0
  if (wave == 1) {
#pragma unroll
    for (int m = 0; m < 4; ++m)
#pragma unroll
      for (int n = 0; n < 4; ++n)
#pragma unroll
        for (int j = 0; j < 4; ++j)
          red[(((((m << 2) | n) << 2) | j) << 6) | lane] = acc[m][n][j];
  }
  __syncthreads();
  if (wave == 0) {
    // epilogue: linear C store + fused per-column sum of squares
    // frag (m,n) elem j: row = tm*64 + m*16 + kcsel*4 + j, col = tn*64 + n*16 + rsel
    const int r0 = tm * 64 + (kcsel << 2);
    const int c0 = tn * 64 + rsel;
    float csq[4] = {0.f, 0.f, 0.f, 0.f};
#pragma unroll
    for (int m = 0; m < 4; ++m)
#pragma unroll
      for (int n = 0; n < 4; ++n)
#pragma unroll
        for (int j = 0; j < 4; ++j) {
          const float v = acc[m][n][j] + red[(((((m << 2) | n) << 2) | j) << 6) | lane];
          C[(size_t)(r0 + m * 16 + j) * 1024 + c0 + n * 16] = v;
          csq[n] += v * v;
        }
#pragma unroll
    for (int n = 0; n < 4; ++n) {
      csq[n] += __shfl_xor(csq[n], 16);
      csq[n] += __shfl_xor(csq[n], 32);
    }
    if (kcsel == 0) {
#pragma unroll
      for (int n = 0; n < 4; ++n)
        atomicAdd(&var[c0 + n * 16], csq[n]);
    }
  }
}

// ---- final: out[b,i] = (1/32) * sum_v act[i][b][v] * wout[v] ----------------
__global__ void final_kernel(const char* __restrict__ ah, const char* __restrict__ al,
                             const float* __restrict__ wout, float* __restrict__ out) {
  const int b = blockIdx.x, tid = threadIdx.x;
  __shared__ float red[3][4];
  float s[3] = {0.f, 0.f, 0.f};
  if (tid < 128) {
    const int v0 = tid * 8;
#pragma unroll
    for (int i = 0; i < 3; ++i) {
      const size_t off = ablk(i * 1024 + b, v0);
      const s16x8 hi = *(const s16x8*)(ah + off);
      const s16x8 lo = *(const s16x8*)(al + off);
#pragma unroll
      for (int j = 0; j < 8; ++j)
        s[i] += (bf2f((unsigned short)hi[j]) + bf2f((unsigned short)lo[j])) * wout[v0 + j];
    }
  }
#pragma unroll
  for (int i = 0; i < 3; ++i)
    for (int o = 32; o >= 1; o >>= 1) s[i] += __shfl_down(s[i], o);
  if ((tid & 63) == 0)
#pragma unroll
    for (int i = 0; i < 3; ++i) red[i][tid >> 6] = s[i];
  __syncthreads();
  if (tid < 3) {
    const float t = red[tid][0] + red[tid][1] + red[tid][2] + red[tid][3];
    out[b * 3 + tid] = t * 0.03125f;
  }
}

extern "C" void kernel_launch(void* const* d_in, const int* in_sizes, int n_in,
                              void* d_out, int out_size, void* d_ws, size_t ws_size,
                              hipStream_t stream) {
  const float* x    = (const float*)d_in[0];
  const float* w1   = (const float*)d_in[1];
  const float* W    = (const float*)d_in[2];
  const float* bnw  = (const float*)d_in[3];
  const float* wout = (const float*)d_in[4];
  float* out = (float*)d_out;

  char* ws = (char*)d_ws;
  float*          var = (float*)ws;                         // 6*1024 f32 (32 KB resv)
  float*          pre = (float*)(ws + 32768);               // C buffer, 12 MB
  char*           ah  = ws + 12615680;                      // blocked bf16 (6 MB)
  char*           al  = ws + 18907136;                      // blocked bf16 (6 MB)
  unsigned short* wh  = (unsigned short*)(ws + 25198592);   // blocked bf16 (10 MB)
  unsigned short* wl  = (unsigned short*)(ws + 35684352);   // blocked bf16 (10 MB)

  hipMemsetAsync(var, 0, 6 * 1024 * sizeof(float), stream);
  convert_w<<<dim3(16, 16, 5), 256, 0, stream>>>(W, wh, wl);
  layer0_fused<<<dim3(4, 64), 256, 0, stream>>>(x, w1, pre, var);
  act_kernel<<<dim3(64, 8), 256, 0, stream>>>(pre, var, bnw, ah, al);
  for (int b = 0; b < 5; ++b) {
    gemm_reg<<<768, 128, 0, stream>>>(
        ah, al, (const char*)(wh + (size_t)b * PLANE), (const char*)(wl + (size_t)b * PLANE),
        pre, var + (b + 1) * 1024);
    act_kernel<<<dim3(64, 8), 256, 0, stream>>>(pre, var + (b + 1) * 1024,
                                                bnw + (size_t)(b + 1) * 4096, ah, al);
  }
  final_kernel<<<1024, 256, 0, stream>>>(ah, al, wout, out);
}

// Round 22
// 193.889 us; speedup vs baseline: 8.6536x; 1.0037x over previous
//
#include <hip/hip_runtime.h>
#include <hip/hip_bf16.h>
#include <cstdint>
#include <cstddef>

// ---------------------------------------------------------------------------
// E3nnMLPNorm: only the l=1 (d=3) irrep path is nonzero.
// R22 = R17/R21 gemm (measured best, ~28us/layer) + non-gemm fusion:
//  - layer0: var computed ANALYTICALLY from x's 3 second moments
//    (var_v = 0.5*(a0^2 M00 + 2 a0 a1 M01 + a1^2 M11)); layer0+BN+gate fused
//    into one kernel reading x directly — 12MB pre write + 12MB read gone.
//  - layer5 act fuses the final dot (atomicAdd, out zeroed by async memset)
//    and skips its activation store — final_kernel + 12MB writes gone.
// ---------------------------------------------------------------------------

typedef short    s16x8 __attribute__((ext_vector_type(8)));
typedef float    f32x4 __attribute__((ext_vector_type(4)));

#define PLANE 1048576   // 1024*1024 elements per plane

__device__ __forceinline__ unsigned short f2bf(float f) {
  unsigned u = __builtin_bit_cast(unsigned, f);
  u += 0x7FFFu + ((u >> 16) & 1u);              // round-to-nearest-even
  return (unsigned short)(u >> 16);
}
__device__ __forceinline__ float bf2f(unsigned short h) {
  return __builtin_bit_cast(float, (unsigned)h << 16);
}

// byte offset of element (row, k) in the K-blocked bf16 operand layout:
// [row>>6][k>>5][(row>>4)&3][(k>>3)&3][row&15][k&7]
__device__ __forceinline__ size_t ablk(int row, int k) {
  return ((size_t)(row >> 6) << 17) + ((size_t)(k >> 5) << 12)
       + ((size_t)((row >> 4) & 3) << 10) + ((size_t)((k >> 3) & 3) << 8)
       + ((size_t)(row & 15) << 4) + ((size_t)(k & 7) << 1);
}

// ---- W[b,0] (f32 [u][v]) -> blocked bf16 hi/lo (row=v, k=u), 1/32 folded ----
__global__ void convert_w(const float* __restrict__ W,
                          unsigned short* __restrict__ Wh,
                          unsigned short* __restrict__ Wl) {
  __shared__ float t[64][65];
  const int u0 = blockIdx.x * 64, v0 = blockIdx.y * 64;
  const float* Wb = W + (size_t)blockIdx.z * 4194304;   // [5][4][1024][1024], irrep 0
  char* Whb = (char*)(Wh + (size_t)blockIdx.z * PLANE);
  char* Wlb = (char*)(Wl + (size_t)blockIdx.z * PLANE);
  const int c = threadIdx.x & 63, r4 = threadIdx.x >> 6;
#pragma unroll
  for (int i = 0; i < 16; ++i) {
    const int r = i * 4 + r4;
    t[r][c] = Wb[(size_t)(u0 + r) * 1024 + v0 + c];
  }
  __syncthreads();
#pragma unroll
  for (int i = 0; i < 16; ++i) {
    const int r = i * 4 + r4;   // local v index
    const float w = t[c][r] * 0.03125f;      // exact pow2 scale
    const unsigned short hi = f2bf(w);
    const size_t off = ablk(v0 + r, u0 + c);
    *(unsigned short*)(Whb + off) = hi;
    *(unsigned short*)(Wlb + off) = f2bf(w - bf2f(hi));
  }
}

// ---- x second moments: M[0]=mean(x0*x0), M[1]=mean(x0*x1), M[2]=mean(x1*x1)
// over all (b, i) pairs (3072). One block, 256 threads.
__global__ void xmoments(const float* __restrict__ x, float* __restrict__ M) {
  float m00 = 0.f, m01 = 0.f, m11 = 0.f;
  for (int b = threadIdx.x; b < 1024; b += 256) {
    const float* xb = x + b * 6;
#pragma unroll
    for (int i = 0; i < 3; ++i) {
      m00 += xb[i] * xb[i];
      m01 += xb[i] * xb[3 + i];
      m11 += xb[3 + i] * xb[3 + i];
    }
  }
  for (int o = 32; o >= 1; o >>= 1) {
    m00 += __shfl_down(m00, o);
    m01 += __shfl_down(m01, o);
    m11 += __shfl_down(m11, o);
  }
  __shared__ float r[3][4];
  if ((threadIdx.x & 63) == 0) {
    r[0][threadIdx.x >> 6] = m00;
    r[1][threadIdx.x >> 6] = m01;
    r[2][threadIdx.x >> 6] = m11;
  }
  __syncthreads();
  if (threadIdx.x < 3)
    M[threadIdx.x] = (r[threadIdx.x][0] + r[threadIdx.x][1] +
                      r[threadIdx.x][2] + r[threadIdx.x][3]) * (1.0f / 3072.0f);
}

// ---- fused layer0 + BN (analytic var) + gate -> blocked bf16 hi/lo ----------
__global__ void layer0_act(const float* __restrict__ x, const float* __restrict__ w1,
                           const float* __restrict__ M, const float* __restrict__ bnw,
                           char* __restrict__ ah, char* __restrict__ al) {
  const int tid = threadIdx.x;
  const int b  = blockIdx.x * 16 + (tid & 15);
  const int v0 = blockIdx.y * 128 + (tid >> 4) * 8;
  const float m00 = M[0], m01 = M[1], m11 = M[2];
  const float* xb = x + b * 6;
  const float x0[3] = {xb[0], xb[1], xb[2]};
  const float x1[3] = {xb[3], xb[4], xb[5]};
  float f[3][8];
#pragma unroll
  for (int j = 0; j < 8; ++j) {
    const float a0 = w1[v0 + j], a1 = w1[1024 + v0 + j];
    const float varv = 0.5f * (a0 * a0 * m00 + 2.f * a0 * a1 * m01 + a1 * a1 * m11);
    const float s = bnw[v0 + j] * 0.70710678118654752f / sqrtf(varv + 1e-5f);
#pragma unroll
    for (int i = 0; i < 3; ++i)
      f[i][j] = (x0[i] * a0 + x1[i] * a1) * s;
  }
#pragma unroll
  for (int j = 0; j < 8; ++j) {
    const float n = sqrtf(f[0][j] * f[0][j] + f[1][j] * f[1][j] + f[2][j] * f[2][j] + 1e-8f);
    const float g = 1.0f / ((1.0f + expf(-n)) * n);   // sigmoid(n)/n
    f[0][j] *= g; f[1][j] *= g; f[2][j] *= g;
  }
#pragma unroll
  for (int i = 0; i < 3; ++i) {
    s16x8 hi, lo;
#pragma unroll
    for (int j = 0; j < 8; ++j) {
      const unsigned short h = f2bf(f[i][j]);
      hi[j] = (short)h;
      lo[j] = (short)f2bf(f[i][j] - bf2f(h));
    }
    const size_t off = ablk(i * 1024 + b, v0);
    *(s16x8*)(ah + off) = hi;
    *(s16x8*)(al + off) = lo;
  }
}

// ---- batchnorm + gate; LAST fuses the output dot, else stores bf16 pairs ----
template <bool LAST>
__global__ void act_kernel(const float* __restrict__ pre, const float* __restrict__ var,
                           const float* __restrict__ bnw,
                           char* __restrict__ ah, char* __restrict__ al,
                           const float* __restrict__ wout, float* __restrict__ out) {
  const int tid = threadIdx.x;
  const int b  = blockIdx.x * 16 + (tid & 15);
  const int v0 = blockIdx.y * 128 + (tid >> 4) * 8;
  float s[8];
#pragma unroll
  for (int j = 0; j < 8; ++j)
    s[j] = bnw[v0 + j] / sqrtf(var[v0 + j] * (1.0f / 3072.0f) + 1e-5f);
  float f[3][8];
#pragma unroll
  for (int i = 0; i < 3; ++i) {
    const float4 p0 = *(const float4*)&pre[(size_t)i * PLANE + (size_t)b * 1024 + v0];
    const float4 p1 = *(const float4*)&pre[(size_t)i * PLANE + (size_t)b * 1024 + v0 + 4];
    f[i][0] = p0.x * s[0]; f[i][1] = p0.y * s[1]; f[i][2] = p0.z * s[2]; f[i][3] = p0.w * s[3];
    f[i][4] = p1.x * s[4]; f[i][5] = p1.y * s[5]; f[i][6] = p1.z * s[6]; f[i][7] = p1.w * s[7];
  }
#pragma unroll
  for (int j = 0; j < 8; ++j) {
    const float n = sqrtf(f[0][j] * f[0][j] + f[1][j] * f[1][j] + f[2][j] * f[2][j] + 1e-8f);
    const float g = 1.0f / ((1.0f + expf(-n)) * n);   // sigmoid(n)/n
    f[0][j] *= g; f[1][j] *= g; f[2][j] *= g;
  }
  if (LAST) {
    // fused final dot: out[b,i] += (1/32) * sum_j f[i][j] * wout[v0+j]
#pragma unroll
    for (int i = 0; i < 3; ++i) {
      float d = 0.f;
#pragma unroll
      for (int j = 0; j < 8; ++j) d += f[i][j] * wout[v0 + j];
      atomicAdd(&out[b * 3 + i], d * 0.03125f);
    }
  } else {
#pragma unroll
    for (int i = 0; i < 3; ++i) {
      s16x8 hi, lo;
#pragma unroll
      for (int j = 0; j < 8; ++j) {
        const unsigned short h = f2bf(f[i][j]);
        hi[j] = (short)h;
        lo[j] = (short)f2bf(f[i][j] - bf2f(h));
      }
      const size_t off = ablk(i * 1024 + b, v0);
      *(s16x8*)(ah + off) = hi;
      *(s16x8*)(al + off) = lo;
    }
  }
}

// ---- K-split x2 direct-to-register bf16-pair MFMA GEMM + fused colsumsq -----
#define LOADF(A_, B_, t_)                                                      \
  {                                                                            \
    const size_t kb_ = (size_t)(t_) << 12;                                     \
    _Pragma("unroll")                                                          \
    for (int m_ = 0; m_ < 4; ++m_) {                                           \
      A_[m_]     = *(const s16x8*)(a_h + kb_ + (m_ << 10));                    \
      A_[4 + m_] = *(const s16x8*)(a_l + kb_ + (m_ << 10));                    \
      B_[m_]     = *(const s16x8*)(b_h + kb_ + (m_ << 10));                    \
      B_[4 + m_] = *(const s16x8*)(b_l + kb_ + (m_ << 10));                    \
    }                                                                          \
  }
#define COMPUTEF(A_, B_)                                                       \
  {                                                                            \
    _Pragma("unroll")                                                          \
    for (int m_ = 0; m_ < 4; ++m_)                                             \
      _Pragma("unroll")                                                        \
      for (int n_ = 0; n_ < 4; ++n_) {                                         \
        acc[m_][n_] = __builtin_amdgcn_mfma_f32_16x16x32_bf16(                 \
            A_[4 + m_], B_[n_], acc[m_][n_], 0, 0, 0);                         \
        acc[m_][n_] = __builtin_amdgcn_mfma_f32_16x16x32_bf16(                 \
            A_[m_], B_[4 + n_], acc[m_][n_], 0, 0, 0);                         \
        acc[m_][n_] = __builtin_amdgcn_mfma_f32_16x16x32_bf16(                 \
            A_[m_], B_[n_], acc[m_][n_], 0, 0, 0);                             \
      }                                                                        \
  }

__global__ __launch_bounds__(128, 2) void gemm_reg(
    const char* __restrict__ Ah, const char* __restrict__ Al,
    const char* __restrict__ Bh, const char* __restrict__ Bl,
    float* __restrict__ C, float* __restrict__ var) {
  __shared__ float red[4096];                     // 16 KB cross-wave handoff
  const int bid = blockIdx.x;
  const int xcd = bid & 7, q = bid >> 3;          // q in 0..95
  const int tm = xcd * 6 + (q % 6);               // 0..47 (XCD M-stripe)
  const int tn = q / 6;                           // 0..15
  const int lane = threadIdx.x & 63;
  const int wave = threadIdx.x >> 6;              // K-half owner: 0 or 1
  const int rsel = lane & 15, kcsel = lane >> 4;

  const size_t la = ((size_t)lane << 4) + ((size_t)wave << 16);
  const char* a_h = Ah + ((size_t)tm << 17) + la;
  const char* a_l = Al + ((size_t)tm << 17) + la;
  const char* b_h = Bh + ((size_t)tn << 17) + la;
  const char* b_l = Bl + ((size_t)tn << 17) + la;

  f32x4 acc[4][4] = {};
  s16x8 A0[8], B0[8], A1[8], B1[8];

  LOADF(A0, B0, 0);
  LOADF(A1, B1, 1);
  for (int t = 0; t < 14; t += 2) {
    COMPUTEF(A0, B0);            // step t
    LOADF(A0, B0, t + 2);
    COMPUTEF(A1, B1);            // step t+1
    LOADF(A1, B1, t + 3);        // last iter loads step 15
  }
  COMPUTEF(A0, B0);              // step 14
  COMPUTEF(A1, B1);              // step 15

  // cross-wave combine: wave1 -> LDS -> wave0
  if (wave == 1) {
#pragma unroll
    for (int m = 0; m < 4; ++m)
#pragma unroll
      for (int n = 0; n < 4; ++n)
#pragma unroll
        for (int j = 0; j < 4; ++j)
          red[(((((m << 2) | n) << 2) | j) << 6) | lane] = acc[m][n][j];
  }
  __syncthreads();
  if (wave == 0) {
    const int r0 = tm * 64 + (kcsel << 2);
    const int c0 = tn * 64 + rsel;
    float csq[4] = {0.f, 0.f, 0.f, 0.f};
#pragma unroll
    for (int m = 0; m < 4; ++m)
#pragma unroll
      for (int n = 0; n < 4; ++n)
#pragma unroll
        for (int j = 0; j < 4; ++j) {
          const float v = acc[m][n][j] + red[(((((m << 2) | n) << 2) | j) << 6) | lane];
          C[(size_t)(r0 + m * 16 + j) * 1024 + c0 + n * 16] = v;
          csq[n] += v * v;
        }
#pragma unroll
    for (int n = 0; n < 4; ++n) {
      csq[n] += __shfl_xor(csq[n], 16);
      csq[n] += __shfl_xor(csq[n], 32);
    }
    if (kcsel == 0) {
#pragma unroll
      for (int n = 0; n < 4; ++n)
        atomicAdd(&var[c0 + n * 16], csq[n]);
    }
  }
}

extern "C" void kernel_launch(void* const* d_in, const int* in_sizes, int n_in,
                              void* d_out, int out_size, void* d_ws, size_t ws_size,
                              hipStream_t stream) {
  const float* x    = (const float*)d_in[0];
  const float* w1   = (const float*)d_in[1];
  const float* W    = (const float*)d_in[2];
  const float* bnw  = (const float*)d_in[3];
  const float* wout = (const float*)d_in[4];
  float* out = (float*)d_out;

  char* ws = (char*)d_ws;
  float*          var = (float*)ws;                         // 6*1024 f32
  float*          Mb  = (float*)(ws + 24576);               // 3 f32 moments
  float*          pre = (float*)(ws + 32768);               // C buffer, 12 MB
  char*           ah  = ws + 12615680;                      // blocked bf16 (6 MB)
  char*           al  = ws + 18907136;                      // blocked bf16 (6 MB)
  unsigned short* wh  = (unsigned short*)(ws + 25198592);   // blocked bf16 (10 MB)
  unsigned short* wl  = (unsigned short*)(ws + 35684352);   // blocked bf16 (10 MB)

  hipMemsetAsync(var, 0, 6 * 1024 * sizeof(float), stream);
  hipMemsetAsync(out, 0, (size_t)out_size * sizeof(float), stream);
  convert_w<<<dim3(16, 16, 5), 256, 0, stream>>>(W, wh, wl);
  xmoments<<<1, 256, 0, stream>>>(x, Mb);
  layer0_act<<<dim3(64, 8), 256, 0, stream>>>(x, w1, Mb, bnw, ah, al);
  for (int b = 0; b < 5; ++b) {
    gemm_reg<<<768, 128, 0, stream>>>(
        ah, al, (const char*)(wh + (size_t)b * PLANE), (const char*)(wl + (size_t)b * PLANE),
        pre, var + (b + 1) * 1024);
    if (b < 4)
      act_kernel<false><<<dim3(64, 8), 256, 0, stream>>>(
          pre, var + (b + 1) * 1024, bnw + (size_t)(b + 1) * 4096,
          ah, al, nullptr, nullptr);
    else
      act_kernel<true><<<dim3(64, 8), 256, 0, stream>>>(
          pre, var + 5 * 1024, bnw + (size_t)5 * 4096,
          ah, al, wout, out);
  }
}